// Round 1
// baseline (699.674 us; speedup 1.0000x reference)
//
#include <hip/hip_runtime.h>
#include <hip/hip_bf16.h>

#define NODES_N 100000
#define EDGES_E 1600000
#define GRAPHS_G 64
#define INDIM 64
#define HIDDIM 128

// ---------------- degree / CSR build ----------------

__global__ void count_edges_k(const int* __restrict__ dst, int E, int* __restrict__ cnt) {
    for (int e = blockIdx.x * blockDim.x + threadIdx.x; e < E; e += gridDim.x * blockDim.x)
        atomicAdd(&cnt[dst[e]], 1);
}

__global__ void dinv_k(const int* __restrict__ cnt, int n, float* __restrict__ dinv) {
    int i = blockIdx.x * blockDim.x + threadIdx.x;
    if (i < n) dinv[i] = rsqrtf((float)cnt[i] + 1.0f);
}

// per-block (1024 elems) sum of cnt
__global__ void count_reduce_k(const int* __restrict__ cnt, int n, int* __restrict__ bsum) {
    __shared__ int sd[256];
    int b = blockIdx.x, t = threadIdx.x;
    int base = b * 1024;
    int s = 0;
    for (int i = t; i < 1024; i += 256) { int idx = base + i; if (idx < n) s += cnt[idx]; }
    sd[t] = s; __syncthreads();
    for (int off = 128; off > 0; off >>= 1) { if (t < off) sd[t] += sd[t + off]; __syncthreads(); }
    if (t == 0) bsum[b] = sd[0];
}

// serial exclusive scan of block sums (nb ~ 98) + write rowptr[n]
__global__ void scan_bsum_k(int* __restrict__ bsum, int nb, int* __restrict__ rowptr, int n, int E) {
    if (blockIdx.x == 0 && threadIdx.x == 0) {
        int acc = 0;
        for (int i = 0; i < nb; i++) { int v = bsum[i]; bsum[i] = acc; acc += v; }
        rowptr[n] = E;
    }
}

// block-level exclusive scan (1024 elems/block, 4/thread) + add block offset
__global__ void write_rowptr_k(const int* __restrict__ cnt, int n, const int* __restrict__ boff,
                               int* __restrict__ rowptr) {
    __shared__ int sd[256];
    int b = blockIdx.x, t = threadIdx.x;
    int base = b * 1024 + t * 4;
    int c0 = 0, c1 = 0, c2 = 0, c3 = 0;
    if (base + 3 < n) {
        int4 v = *(const int4*)&cnt[base];
        c0 = v.x; c1 = v.y; c2 = v.z; c3 = v.w;
    } else {
        if (base     < n) c0 = cnt[base];
        if (base + 1 < n) c1 = cnt[base + 1];
        if (base + 2 < n) c2 = cnt[base + 2];
        if (base + 3 < n) c3 = cnt[base + 3];
    }
    int tsum = c0 + c1 + c2 + c3;
    sd[t] = tsum; __syncthreads();
    // inclusive Hillis-Steele
    for (int off = 1; off < 256; off <<= 1) {
        int x = (t >= off) ? sd[t - off] : 0;
        __syncthreads();
        sd[t] += x;
        __syncthreads();
    }
    int excl = sd[t] - tsum + boff[b];
    if (base     < n) rowptr[base]     = excl;
    if (base + 1 < n) rowptr[base + 1] = excl + c0;
    if (base + 2 < n) rowptr[base + 2] = excl + c0 + c1;
    if (base + 3 < n) rowptr[base + 3] = excl + c0 + c1 + c2;
}

__global__ void fill_csr_k(const int* __restrict__ src, const int* __restrict__ dst, int E,
                           const int* __restrict__ rowptr, int* __restrict__ cursor,
                           int* __restrict__ colidx) {
    for (int e = blockIdx.x * blockDim.x + threadIdx.x; e < E; e += gridDim.x * blockDim.x) {
        int d = dst[e];
        int pos = rowptr[d] + atomicAdd(&cursor[d], 1);
        colidx[pos] = src[e];
    }
}

// ---------------- GEMM: out[row, jbase+j] = (X[row,:] @ W[:, jbase+j]) * dinv[row] ----------------
// W is [K,128] row-major. NJ = channels handled per block (gridDim.y = 128/NJ).

template <int K, int NJ>
__global__ __launch_bounds__(256) void gemm_scale_k(const float* __restrict__ X,
                                                    const float* __restrict__ W,
                                                    const float* __restrict__ dinv,
                                                    float* __restrict__ out, int n) {
    constexpr int JL = NJ / 4;       // lanes covering channels
    constexpr int R  = 256 / JL;     // rows per tile
    __shared__ float Wl[K][NJ];
    __shared__ float Xl[R][K + 4];
    int t = threadIdx.x;
    int jbase = blockIdx.y * NJ;
    // stage W (L2-resident, tiny)
    for (int i = t; i < K * JL; i += 256) {
        int k = i / JL, j = (i % JL) * 4;
        *(float4*)&Wl[k][j] = *(const float4*)&W[k * 128 + jbase + j];
    }
    int tiles = (n + R - 1) / R;
    for (int tile = blockIdx.x; tile < tiles; tile += gridDim.x) {
        int row0 = tile * R;
        __syncthreads();
        for (int i = t; i < R * (K / 4); i += 256) {
            int r = i / (K / 4), c = (i % (K / 4)) * 4;
            int row = row0 + r;
            float4 v = make_float4(0.f, 0.f, 0.f, 0.f);
            if (row < n) v = *(const float4*)&X[row * K + c];
            *(float4*)&Xl[r][c] = v;
        }
        __syncthreads();
        int r = t / JL;
        int j = (t % JL) * 4;
        float ax = 0.f, ay = 0.f, az = 0.f, aw = 0.f;
#pragma unroll
        for (int k = 0; k < K; k++) {
            float xv = Xl[r][k];
            float4 w = *(const float4*)&Wl[k][j];
            ax = fmaf(xv, w.x, ax);
            ay = fmaf(xv, w.y, ay);
            az = fmaf(xv, w.z, az);
            aw = fmaf(xv, w.w, aw);
        }
        int row = row0 + r;
        if (row < n) {
            float s = dinv[row];
            float4 o = make_float4(ax * s, ay * s, az * s, aw * s);
            *(float4*)&out[row * 128 + jbase + j] = o;
        }
    }
}

// ---------------- gather: out[d] = relu(dinv[d]*(h'[d] + sum_{src in CSR[d]} h'[src]) + b) ----------------

__global__ __launch_bounds__(256) void gcn_gather_k(const float* __restrict__ h,
                                                    const int* __restrict__ rowptr,
                                                    const int* __restrict__ colidx,
                                                    const float* __restrict__ dinv,
                                                    const float* __restrict__ bias,
                                                    float* __restrict__ out, int n) {
    int lane = threadIdx.x & 31;
    int local = threadIdx.x >> 5;   // 8 nodes per block
    int co = lane * 4;
    for (int node = blockIdx.x * 8 + local; node < n; node += gridDim.x * 8) {
        float4 acc = *(const float4*)&h[(size_t)node * 128 + co];  // self message
        int beg = rowptr[node], end = rowptr[node + 1];
        for (int e = beg; e < end; e++) {
            int s = colidx[e];
            float4 v = *(const float4*)&h[(size_t)s * 128 + co];
            acc.x += v.x; acc.y += v.y; acc.z += v.z; acc.w += v.w;
        }
        float dv = dinv[node];
        float4 b = *(const float4*)&bias[co];
        float4 o;
        o.x = fmaxf(fmaf(dv, acc.x, b.x), 0.f);
        o.y = fmaxf(fmaf(dv, acc.y, b.y), 0.f);
        o.z = fmaxf(fmaf(dv, acc.z, b.z), 0.f);
        o.w = fmaxf(fmaf(dv, acc.w, b.w), 0.f);
        *(float4*)&out[(size_t)node * 128 + co] = o;
    }
}

// ---------------- pool: sums[g,:] += h[i,:], cnts[g] += 1 (batch sorted -> flush on change) ----------------

__global__ __launch_bounds__(128) void pool_k(const float* __restrict__ h,
                                              const int* __restrict__ batch, int n,
                                              float* __restrict__ sums, float* __restrict__ cnts) {
    int j = threadIdx.x;
    int chunk = (n + gridDim.x - 1) / gridDim.x;
    int i0 = blockIdx.x * chunk;
    int i1 = min(n, i0 + chunk);
    if (i0 >= n) return;
    int cur = batch[i0];
    float acc = 0.f;
    int cnt = 0;
    for (int i = i0; i < i1; i++) {
        int g = batch[i];
        if (g != cur) {
            atomicAdd(&sums[cur * 128 + j], acc);
            if (j == 0) atomicAdd(&cnts[cur], (float)cnt);
            acc = 0.f; cnt = 0; cur = g;
        }
        acc += h[(size_t)i * 128 + j];
        cnt++;
    }
    atomicAdd(&sums[cur * 128 + j], acc);
    if (j == 0) atomicAdd(&cnts[cur], (float)cnt);
}

// ---------------- MLP head: one block per graph ----------------

__global__ __launch_bounds__(64) void mlp_k(const float* __restrict__ sums, const float* __restrict__ cnts,
                                            const float* __restrict__ Wl1, const float* __restrict__ bl1,
                                            const float* __restrict__ Wl2, const float* __restrict__ bl2,
                                            float* __restrict__ out) {
    __shared__ float pooled[128];
    __shared__ float hidden[64];
    int g = blockIdx.x, t = threadIdx.x;
    float c = fmaxf(cnts[g], 1.0f);
    pooled[t]      = sums[g * 128 + t] / c;
    pooled[t + 64] = sums[g * 128 + 64 + t] / c;
    __syncthreads();
    float a = bl1[t];
#pragma unroll 4
    for (int cc = 0; cc < 128; cc++) a = fmaf(pooled[cc], Wl1[cc * 64 + t], a);
    hidden[t] = fmaxf(a, 0.f);
    __syncthreads();
    if (t < 10) {
        float o = bl2[t];
#pragma unroll 8
        for (int jj = 0; jj < 64; jj++) o = fmaf(hidden[jj], Wl2[jj * 10 + t], o);
        out[g * 10 + t] = o;
    }
}

// ---------------- launch ----------------

extern "C" void kernel_launch(void* const* d_in, const int* in_sizes, int n_in,
                              void* d_out, int out_size, void* d_ws, size_t ws_size,
                              hipStream_t stream) {
    const float* x    = (const float*)d_in[0];
    const int*   src  = (const int*)d_in[1];
    const int*   dst  = (const int*)d_in[2];
    const int*   batch= (const int*)d_in[3];
    const float* W1   = (const float*)d_in[4];
    const float* b1   = (const float*)d_in[5];
    const float* W2   = (const float*)d_in[6];
    const float* b2   = (const float*)d_in[7];
    const float* Wl1  = (const float*)d_in[8];
    const float* bl1  = (const float*)d_in[9];
    const float* Wl2  = (const float*)d_in[10];
    const float* bl2  = (const float*)d_in[11];
    float* out = (float*)d_out;

    const int N = NODES_N, E = EDGES_E;

    // workspace layout (256B aligned chunks)
    size_t off = 0;
    auto take = [&](size_t bytes) { size_t o = off; off = (off + bytes + 255) & ~(size_t)255; return o; };
    char* ws = (char*)d_ws;
    float* bufA   = (float*)(ws + take((size_t)N * 128 * 4));
    float* bufB   = (float*)(ws + take((size_t)N * 128 * 4));
    float* dinv   = (float*)(ws + take((size_t)N * 4));
    // contiguous zero region: cnt, cursor, sums, cnts
    size_t zbytes = ((size_t)N + N + GRAPHS_G * 128 + GRAPHS_G) * 4;
    char*  zbase  = ws + take(zbytes);
    int*   cnt    = (int*)zbase;
    int*   cursor = (int*)(zbase + (size_t)N * 4);
    float* sums   = (float*)(zbase + (size_t)2 * N * 4);
    float* cnts   = (float*)(zbase + (size_t)2 * N * 4 + GRAPHS_G * 128 * 4);
    int*   rowptr = (int*)(ws + take((size_t)(N + 1) * 4));
    int*   bsum   = (int*)(ws + take(256 * 4));
    int*   colidx = (int*)(ws + take((size_t)E * 4));
    (void)ws_size; (void)in_sizes; (void)n_in; (void)out_size;

    hipMemsetAsync(zbase, 0, zbytes, stream);

    // degree + CSR
    count_edges_k<<<2048, 256, 0, stream>>>(dst, E, cnt);
    dinv_k<<<(N + 255) / 256, 256, 0, stream>>>(cnt, N, dinv);
    int nb = (N + 1023) / 1024;
    count_reduce_k<<<nb, 256, 0, stream>>>(cnt, N, bsum);
    scan_bsum_k<<<1, 64, 0, stream>>>(bsum, nb, rowptr, N, E);
    write_rowptr_k<<<nb, 256, 0, stream>>>(cnt, N, bsum, rowptr);
    fill_csr_k<<<2048, 256, 0, stream>>>(src, dst, E, rowptr, cursor, colidx);

    // conv1: h1' = (x @ W1) * dinv ; h1 = relu(dinv*(self+neigh) + b1)
    gemm_scale_k<INDIM, 128><<<dim3(2048, 1), 256, 0, stream>>>(x, W1, dinv, bufA, N);
    gcn_gather_k<<<2048, 256, 0, stream>>>(bufA, rowptr, colidx, dinv, b1, bufB, N);

    // conv2
    gemm_scale_k<HIDDIM, 64><<<dim3(2048, 2), 256, 0, stream>>>(bufB, W2, dinv, bufA, N);
    gcn_gather_k<<<2048, 256, 0, stream>>>(bufA, rowptr, colidx, dinv, b2, bufB, N);

    // pool + head
    pool_k<<<256, 128, 0, stream>>>(bufB, batch, N, sums, cnts);
    mlp_k<<<GRAPHS_G, 64, 0, stream>>>(sums, cnts, Wl1, bl1, Wl2, bl2, out);
}

// Round 2
// 476.394 us; speedup vs baseline: 1.4687x; 1.4687x over previous
//
#include <hip/hip_runtime.h>
#include <hip/hip_bf16.h>

#define NODES_N 100000
#define EDGES_E 1600000
#define GRAPHS_G 64

typedef unsigned int uint;

// ---------------- helpers ----------------

__device__ inline uint pack_bf2(float lo, float hi) {
    __hip_bfloat162 h2 = __float22bfloat162_rn(make_float2(lo, hi));
    return *reinterpret_cast<uint*>(&h2);
}

__device__ inline void acc_bf2(uint w, float& a0, float& a1) {
    a0 += __uint_as_float(w << 16);
    a1 += __uint_as_float(w & 0xffff0000u);
}

// ---------------- degree / CSR build ----------------

__global__ void count_edges_k(const int* __restrict__ dst, int E, int* __restrict__ cnt) {
    for (int e = blockIdx.x * blockDim.x + threadIdx.x; e < E; e += gridDim.x * blockDim.x)
        atomicAdd(&cnt[dst[e]], 1);
}

__global__ void dinv_k(const int* __restrict__ cnt, int n, float* __restrict__ dinv) {
    int i = blockIdx.x * blockDim.x + threadIdx.x;
    if (i < n) dinv[i] = rsqrtf((float)cnt[i] + 1.0f);
}

__global__ void count_reduce_k(const int* __restrict__ cnt, int n, int* __restrict__ bsum) {
    __shared__ int sd[256];
    int b = blockIdx.x, t = threadIdx.x;
    int base = b * 1024;
    int s = 0;
    for (int i = t; i < 1024; i += 256) { int idx = base + i; if (idx < n) s += cnt[idx]; }
    sd[t] = s; __syncthreads();
    for (int off = 128; off > 0; off >>= 1) { if (t < off) sd[t] += sd[t + off]; __syncthreads(); }
    if (t == 0) bsum[b] = sd[0];
}

__global__ void scan_bsum_k(int* __restrict__ bsum, int nb, int* __restrict__ rowptr, int n, int E) {
    if (blockIdx.x == 0 && threadIdx.x == 0) {
        int acc = 0;
        for (int i = 0; i < nb; i++) { int v = bsum[i]; bsum[i] = acc; acc += v; }
        rowptr[n] = E;
    }
}

__global__ void write_rowptr_k(const int* __restrict__ cnt, int n, const int* __restrict__ boff,
                               int* __restrict__ rowptr) {
    __shared__ int sd[256];
    int b = blockIdx.x, t = threadIdx.x;
    int base = b * 1024 + t * 4;
    int c0 = 0, c1 = 0, c2 = 0, c3 = 0;
    if (base + 3 < n) {
        int4 v = *(const int4*)&cnt[base];
        c0 = v.x; c1 = v.y; c2 = v.z; c3 = v.w;
    } else {
        if (base     < n) c0 = cnt[base];
        if (base + 1 < n) c1 = cnt[base + 1];
        if (base + 2 < n) c2 = cnt[base + 2];
        if (base + 3 < n) c3 = cnt[base + 3];
    }
    int tsum = c0 + c1 + c2 + c3;
    sd[t] = tsum; __syncthreads();
    for (int off = 1; off < 256; off <<= 1) {
        int x = (t >= off) ? sd[t - off] : 0;
        __syncthreads();
        sd[t] += x;
        __syncthreads();
    }
    int excl = sd[t] - tsum + boff[b];
    if (base     < n) rowptr[base]     = excl;
    if (base + 1 < n) rowptr[base + 1] = excl + c0;
    if (base + 2 < n) rowptr[base + 2] = excl + c0 + c1;
    if (base + 3 < n) rowptr[base + 3] = excl + c0 + c1 + c2;
}

__global__ void fill_csr_k(const int* __restrict__ src, const int* __restrict__ dst, int E,
                           const int* __restrict__ rowptr, int* __restrict__ cursor,
                           int* __restrict__ colidx) {
    for (int e = blockIdx.x * blockDim.x + threadIdx.x; e < E; e += gridDim.x * blockDim.x) {
        int d = dst[e];
        int pos = rowptr[d] + atomicAdd(&cursor[d], 1);
        colidx[pos] = src[e];
    }
}

// ---------------- x~ = bf16(x * dinv[row])  [N,64] ----------------

__global__ __launch_bounds__(256) void scale_x_k(const float* __restrict__ x,
                                                 const float* __restrict__ dinv,
                                                 uint* __restrict__ xt, int n) {
    int gid = blockIdx.x * blockDim.x + threadIdx.x;
    if (gid >= n * 8) return;
    int row = gid >> 3, l = gid & 7;
    float dv = dinv[row];
    const float* p = &x[(size_t)row * 64 + l * 8];
    float4 a = *(const float4*)p;
    float4 b = *(const float4*)(p + 4);
    uint4 o;
    o.x = pack_bf2(a.x * dv, a.y * dv);
    o.y = pack_bf2(a.z * dv, a.w * dv);
    o.z = pack_bf2(b.x * dv, b.y * dv);
    o.w = pack_bf2(b.z * dv, b.w * dv);
    *(uint4*)&xt[(size_t)row * 32 + l * 4] = o;
}

// ---------------- gather 64-dim bf16 -> f32 sum: s[d] = xt[d] + sum xt[src] ----------------
// 8 lanes/node, 16B per lane

__global__ __launch_bounds__(256) void gather64_k(const uint* __restrict__ xt,
                                                  const int* __restrict__ rowptr,
                                                  const int* __restrict__ colidx,
                                                  float* __restrict__ s, int n) {
    int lane = threadIdx.x & 7;
    int local = threadIdx.x >> 3;   // 32 nodes/block
    int co = lane * 4;              // uint offset in row of 32 uints
    for (int node = blockIdx.x * 32 + local; node < n; node += gridDim.x * 32) {
        float a0=0,a1=0,a2=0,a3=0,a4=0,a5=0,a6=0,a7=0;
        uint4 v = *(const uint4*)&xt[(size_t)node * 32 + co];
        acc_bf2(v.x, a0, a1); acc_bf2(v.y, a2, a3);
        acc_bf2(v.z, a4, a5); acc_bf2(v.w, a6, a7);
        int beg = rowptr[node], end = rowptr[node + 1];
        int e = beg;
        for (; e + 3 < end; e += 4) {
            int s0 = colidx[e], s1 = colidx[e+1], s2 = colidx[e+2], s3 = colidx[e+3];
            uint4 v0 = *(const uint4*)&xt[(size_t)s0 * 32 + co];
            uint4 v1 = *(const uint4*)&xt[(size_t)s1 * 32 + co];
            uint4 v2 = *(const uint4*)&xt[(size_t)s2 * 32 + co];
            uint4 v3 = *(const uint4*)&xt[(size_t)s3 * 32 + co];
            acc_bf2(v0.x,a0,a1); acc_bf2(v0.y,a2,a3); acc_bf2(v0.z,a4,a5); acc_bf2(v0.w,a6,a7);
            acc_bf2(v1.x,a0,a1); acc_bf2(v1.y,a2,a3); acc_bf2(v1.z,a4,a5); acc_bf2(v1.w,a6,a7);
            acc_bf2(v2.x,a0,a1); acc_bf2(v2.y,a2,a3); acc_bf2(v2.z,a4,a5); acc_bf2(v2.w,a6,a7);
            acc_bf2(v3.x,a0,a1); acc_bf2(v3.y,a2,a3); acc_bf2(v3.z,a4,a5); acc_bf2(v3.w,a6,a7);
        }
        for (; e < end; e++) {
            uint4 v0 = *(const uint4*)&xt[(size_t)colidx[e] * 32 + co];
            acc_bf2(v0.x,a0,a1); acc_bf2(v0.y,a2,a3); acc_bf2(v0.z,a4,a5); acc_bf2(v0.w,a6,a7);
        }
        float* o = &s[(size_t)node * 64 + lane * 8];
        *(float4*)o       = make_float4(a0, a1, a2, a3);
        *(float4*)(o + 4) = make_float4(a4, a5, a6, a7);
    }
}

// ---------------- gather 128-dim bf16 -> out = relu(dinv*(self+sum) + b) f32 ----------------
// 16 lanes/node, 16B per lane

__global__ __launch_bounds__(256) void gather128_k(const uint* __restrict__ hp,
                                                   const int* __restrict__ rowptr,
                                                   const int* __restrict__ colidx,
                                                   const float* __restrict__ dinv,
                                                   const float* __restrict__ bias,
                                                   float* __restrict__ out, int n) {
    int lane = threadIdx.x & 15;
    int local = threadIdx.x >> 4;   // 16 nodes/block
    int co = lane * 4;              // uint offset in row of 64 uints
    for (int node = blockIdx.x * 16 + local; node < n; node += gridDim.x * 16) {
        float a0=0,a1=0,a2=0,a3=0,a4=0,a5=0,a6=0,a7=0;
        uint4 v = *(const uint4*)&hp[(size_t)node * 64 + co];
        acc_bf2(v.x, a0, a1); acc_bf2(v.y, a2, a3);
        acc_bf2(v.z, a4, a5); acc_bf2(v.w, a6, a7);
        int beg = rowptr[node], end = rowptr[node + 1];
        int e = beg;
        for (; e + 3 < end; e += 4) {
            int s0 = colidx[e], s1 = colidx[e+1], s2 = colidx[e+2], s3 = colidx[e+3];
            uint4 v0 = *(const uint4*)&hp[(size_t)s0 * 64 + co];
            uint4 v1 = *(const uint4*)&hp[(size_t)s1 * 64 + co];
            uint4 v2 = *(const uint4*)&hp[(size_t)s2 * 64 + co];
            uint4 v3 = *(const uint4*)&hp[(size_t)s3 * 64 + co];
            acc_bf2(v0.x,a0,a1); acc_bf2(v0.y,a2,a3); acc_bf2(v0.z,a4,a5); acc_bf2(v0.w,a6,a7);
            acc_bf2(v1.x,a0,a1); acc_bf2(v1.y,a2,a3); acc_bf2(v1.z,a4,a5); acc_bf2(v1.w,a6,a7);
            acc_bf2(v2.x,a0,a1); acc_bf2(v2.y,a2,a3); acc_bf2(v2.z,a4,a5); acc_bf2(v2.w,a6,a7);
            acc_bf2(v3.x,a0,a1); acc_bf2(v3.y,a2,a3); acc_bf2(v3.z,a4,a5); acc_bf2(v3.w,a6,a7);
        }
        for (; e < end; e++) {
            uint4 v0 = *(const uint4*)&hp[(size_t)colidx[e] * 64 + co];
            acc_bf2(v0.x,a0,a1); acc_bf2(v0.y,a2,a3); acc_bf2(v0.z,a4,a5); acc_bf2(v0.w,a6,a7);
        }
        float dv = dinv[node];
        int jb = lane * 8;
        float4 b0 = *(const float4*)&bias[jb];
        float4 b1 = *(const float4*)&bias[jb + 4];
        float4 o0, o1;
        o0.x = fmaxf(fmaf(dv, a0, b0.x), 0.f);
        o0.y = fmaxf(fmaf(dv, a1, b0.y), 0.f);
        o0.z = fmaxf(fmaf(dv, a2, b0.z), 0.f);
        o0.w = fmaxf(fmaf(dv, a3, b0.w), 0.f);
        o1.x = fmaxf(fmaf(dv, a4, b1.x), 0.f);
        o1.y = fmaxf(fmaf(dv, a5, b1.y), 0.f);
        o1.z = fmaxf(fmaf(dv, a6, b1.z), 0.f);
        o1.w = fmaxf(fmaf(dv, a7, b1.w), 0.f);
        float* o = &out[(size_t)node * 128 + jb];
        *(float4*)o       = o0;
        *(float4*)(o + 4) = o1;
    }
}

// ---------------- GEMM with epilogue ----------------
// X [n,K] f32, W [K,128] row-major. EPI 0: relu(dinv*a + bias) -> f32 [n,128]
//                                   EPI 1: bf16(dinv*a)        -> bf16 [n,128] (as uint[n,64])

template <int K, int NJ, int EPI>
__global__ __launch_bounds__(256) void gemm_epi_k(const float* __restrict__ X,
                                                  const float* __restrict__ W,
                                                  const float* __restrict__ dinv,
                                                  const float* __restrict__ bias,
                                                  float* __restrict__ outf,
                                                  uint* __restrict__ outb, int n) {
    constexpr int JL = NJ / 4;
    constexpr int R  = 256 / JL;
    __shared__ float Wl[K][NJ];
    __shared__ float Xl[R][K + 4];
    int t = threadIdx.x;
    int jbase = blockIdx.y * NJ;
    for (int i = t; i < K * JL; i += 256) {
        int k = i / JL, j = (i % JL) * 4;
        *(float4*)&Wl[k][j] = *(const float4*)&W[k * 128 + jbase + j];
    }
    int tiles = (n + R - 1) / R;
    for (int tile = blockIdx.x; tile < tiles; tile += gridDim.x) {
        int row0 = tile * R;
        __syncthreads();
        for (int i = t; i < R * (K / 4); i += 256) {
            int r = i / (K / 4), c = (i % (K / 4)) * 4;
            int row = row0 + r;
            float4 v = make_float4(0.f, 0.f, 0.f, 0.f);
            if (row < n) v = *(const float4*)&X[(size_t)row * K + c];
            *(float4*)&Xl[r][c] = v;
        }
        __syncthreads();
        int r = t / JL;
        int j = (t % JL) * 4;
        float ax = 0.f, ay = 0.f, az = 0.f, aw = 0.f;
#pragma unroll
        for (int k = 0; k < K; k++) {
            float xv = Xl[r][k];
            float4 w = *(const float4*)&Wl[k][j];
            ax = fmaf(xv, w.x, ax);
            ay = fmaf(xv, w.y, ay);
            az = fmaf(xv, w.z, az);
            aw = fmaf(xv, w.w, aw);
        }
        int row = row0 + r;
        if (row < n) {
            float dv = dinv[row];
            if (EPI == 0) {
                float4 b = *(const float4*)&bias[jbase + j];
                float4 o;
                o.x = fmaxf(fmaf(dv, ax, b.x), 0.f);
                o.y = fmaxf(fmaf(dv, ay, b.y), 0.f);
                o.z = fmaxf(fmaf(dv, az, b.z), 0.f);
                o.w = fmaxf(fmaf(dv, aw, b.w), 0.f);
                *(float4*)&outf[(size_t)row * 128 + jbase + j] = o;
            } else {
                uint2 p;
                p.x = pack_bf2(ax * dv, ay * dv);
                p.y = pack_bf2(az * dv, aw * dv);
                *(uint2*)&outb[(size_t)row * 64 + (jbase + j) / 2] = p;
            }
        }
    }
}

// ---------------- pool ----------------

__global__ __launch_bounds__(128) void pool_k(const float* __restrict__ h,
                                              const int* __restrict__ batch, int n,
                                              float* __restrict__ sums, float* __restrict__ cnts) {
    int j = threadIdx.x;
    int chunk = (n + gridDim.x - 1) / gridDim.x;
    int i0 = blockIdx.x * chunk;
    int i1 = min(n, i0 + chunk);
    if (i0 >= n) return;
    int cur = batch[i0];
    float acc = 0.f;
    int cnt = 0;
    for (int i = i0; i < i1; i++) {
        int g = batch[i];
        if (g != cur) {
            atomicAdd(&sums[cur * 128 + j], acc);
            if (j == 0) atomicAdd(&cnts[cur], (float)cnt);
            acc = 0.f; cnt = 0; cur = g;
        }
        acc += h[(size_t)i * 128 + j];
        cnt++;
    }
    atomicAdd(&sums[cur * 128 + j], acc);
    if (j == 0) atomicAdd(&cnts[cur], (float)cnt);
}

// ---------------- MLP head ----------------

__global__ __launch_bounds__(64) void mlp_k(const float* __restrict__ sums, const float* __restrict__ cnts,
                                            const float* __restrict__ Wl1, const float* __restrict__ bl1,
                                            const float* __restrict__ Wl2, const float* __restrict__ bl2,
                                            float* __restrict__ out) {
    __shared__ float pooled[128];
    __shared__ float hidden[64];
    int g = blockIdx.x, t = threadIdx.x;
    float c = fmaxf(cnts[g], 1.0f);
    pooled[t]      = sums[g * 128 + t] / c;
    pooled[t + 64] = sums[g * 128 + 64 + t] / c;
    __syncthreads();
    float a = bl1[t];
#pragma unroll 4
    for (int cc = 0; cc < 128; cc++) a = fmaf(pooled[cc], Wl1[cc * 64 + t], a);
    hidden[t] = fmaxf(a, 0.f);
    __syncthreads();
    if (t < 10) {
        float o = bl2[t];
#pragma unroll 8
        for (int jj = 0; jj < 64; jj++) o = fmaf(hidden[jj], Wl2[jj * 10 + t], o);
        out[g * 10 + t] = o;
    }
}

// ---------------- launch ----------------

extern "C" void kernel_launch(void* const* d_in, const int* in_sizes, int n_in,
                              void* d_out, int out_size, void* d_ws, size_t ws_size,
                              hipStream_t stream) {
    const float* x    = (const float*)d_in[0];
    const int*   src  = (const int*)d_in[1];
    const int*   dst  = (const int*)d_in[2];
    const int*   batch= (const int*)d_in[3];
    const float* W1   = (const float*)d_in[4];
    const float* b1   = (const float*)d_in[5];
    const float* W2   = (const float*)d_in[6];
    const float* b2   = (const float*)d_in[7];
    const float* Wl1  = (const float*)d_in[8];
    const float* bl1  = (const float*)d_in[9];
    const float* Wl2  = (const float*)d_in[10];
    const float* bl2  = (const float*)d_in[11];
    float* out = (float*)d_out;

    const int N = NODES_N, E = EDGES_E;

    size_t off = 0;
    auto take = [&](size_t bytes) { size_t o = off; off = (off + bytes + 255) & ~(size_t)255; return o; };
    char* ws = (char*)d_ws;
    float* bufA   = (float*)(ws + take((size_t)N * 128 * 4));   // h1 f32
    float* bufB   = (float*)(ws + take((size_t)N * 128 * 4));   // h2 f32
    float* sbuf   = (float*)(ws + take((size_t)N * 64 * 4));    // s f32; reused as h2' bf16
    uint*  xt     = (uint*)(ws + take((size_t)N * 32 * 4));     // x~ bf16 [N,64]
    float* dinv   = (float*)(ws + take((size_t)N * 4));
    size_t zbytes = ((size_t)N + N + GRAPHS_G * 128 + GRAPHS_G) * 4;
    char*  zbase  = ws + take(zbytes);
    int*   cnt    = (int*)zbase;
    int*   cursor = (int*)(zbase + (size_t)N * 4);
    float* sums   = (float*)(zbase + (size_t)2 * N * 4);
    float* cnts   = (float*)(zbase + (size_t)2 * N * 4 + GRAPHS_G * 128 * 4);
    int*   rowptr = (int*)(ws + take((size_t)(N + 1) * 4));
    int*   bsum   = (int*)(ws + take(256 * 4));
    int*   colidx = (int*)(ws + take((size_t)E * 4));
    uint*  h2p    = (uint*)sbuf;                                // bf16 [N,128] as uint[N,64]
    (void)ws_size; (void)in_sizes; (void)n_in; (void)out_size;

    hipMemsetAsync(zbase, 0, zbytes, stream);

    // degree + CSR
    count_edges_k<<<2048, 256, 0, stream>>>(dst, E, cnt);
    dinv_k<<<(N + 255) / 256, 256, 0, stream>>>(cnt, N, dinv);
    int nb = (N + 1023) / 1024;
    count_reduce_k<<<nb, 256, 0, stream>>>(cnt, N, bsum);
    scan_bsum_k<<<1, 64, 0, stream>>>(bsum, nb, rowptr, N, E);
    write_rowptr_k<<<nb, 256, 0, stream>>>(cnt, N, bsum, rowptr);
    fill_csr_k<<<2048, 256, 0, stream>>>(src, dst, E, rowptr, cursor, colidx);

    // conv1 (aggregate-first): s = xt[self] + sum xt[src]; h1 = relu(dinv*(s@W1) + b1)
    scale_x_k<<<(N * 8 + 255) / 256, 256, 0, stream>>>(x, dinv, xt, N);
    gather64_k<<<2048, 256, 0, stream>>>(xt, rowptr, colidx, sbuf, N);
    gemm_epi_k<64, 128, 0><<<dim3(2048, 1), 256, 0, stream>>>(sbuf, W1, dinv, b1, bufA, nullptr, N);

    // conv2: h2' = bf16(dinv*(h1@W2)); h2 = relu(dinv*(self+sum) + b2)
    gemm_epi_k<128, 64, 1><<<dim3(2048, 2), 256, 0, stream>>>(bufA, W2, dinv, b2, nullptr, h2p, N);
    gather128_k<<<2048, 256, 0, stream>>>(h2p, rowptr, colidx, dinv, b2, bufB, N);

    // pool + head
    pool_k<<<1024, 128, 0, stream>>>(bufB, batch, N, sums, cnts);
    mlp_k<<<GRAPHS_G, 64, 0, stream>>>(sums, cnts, Wl1, bl1, Wl2, bl2, out);
}

// Round 3
// 300.478 us; speedup vs baseline: 2.3285x; 1.5855x over previous
//
#include <hip/hip_runtime.h>
#include <hip/hip_bf16.h>

#define NODES_N 100000
#define EDGES_E 1600000
#define GRAPHS_G 64

typedef unsigned int uint;
typedef unsigned short ushort;
typedef __attribute__((ext_vector_type(8))) short bf16x8;
typedef __attribute__((ext_vector_type(4))) float f32x4;

// ---------------- helpers ----------------

__device__ inline uint pack_bf2(float lo, float hi) {
    __hip_bfloat162 h2 = __float22bfloat162_rn(make_float2(lo, hi));
    return *reinterpret_cast<uint*>(&h2);
}

__device__ inline void acc_bf2(uint w, float& a0, float& a1) {
    a0 += __uint_as_float(w << 16);
    a1 += __uint_as_float(w & 0xffff0000u);
}

__device__ inline ushort f2bf(float v) {
    __hip_bfloat16 b = __float2bfloat16(v);
    return *reinterpret_cast<ushort*>(&b);
}

// ---------------- degree count + per-edge rank ----------------

__global__ void count_rank_k(const int* __restrict__ dst, int E,
                             int* __restrict__ cnt, int* __restrict__ rank) {
    for (int e = blockIdx.x * blockDim.x + threadIdx.x; e < E; e += gridDim.x * blockDim.x) {
        int d = dst[e];
        rank[e] = atomicAdd(&cnt[d], 1);
    }
}

__global__ void dinv_k(const int* __restrict__ cnt, int n, float* __restrict__ dinv) {
    int i = blockIdx.x * blockDim.x + threadIdx.x;
    if (i < n) dinv[i] = rsqrtf((float)cnt[i] + 1.0f);
}

__global__ void count_reduce_k(const int* __restrict__ cnt, int n, int* __restrict__ bsum) {
    __shared__ int sd[256];
    int b = blockIdx.x, t = threadIdx.x;
    int base = b * 1024;
    int s = 0;
    for (int i = t; i < 1024; i += 256) { int idx = base + i; if (idx < n) s += cnt[idx]; }
    sd[t] = s; __syncthreads();
    for (int off = 128; off > 0; off >>= 1) { if (t < off) sd[t] += sd[t + off]; __syncthreads(); }
    if (t == 0) bsum[b] = sd[0];
}

__global__ void scan_bsum_k(int* __restrict__ bsum, int nb, int* __restrict__ rowptr, int n, int E) {
    if (blockIdx.x == 0 && threadIdx.x == 0) {
        int acc = 0;
        for (int i = 0; i < nb; i++) { int v = bsum[i]; bsum[i] = acc; acc += v; }
        rowptr[n] = E;
    }
}

__global__ void write_rowptr_k(const int* __restrict__ cnt, int n, const int* __restrict__ boff,
                               int* __restrict__ rowptr) {
    __shared__ int sd[256];
    int b = blockIdx.x, t = threadIdx.x;
    int base = b * 1024 + t * 4;
    int c0 = 0, c1 = 0, c2 = 0, c3 = 0;
    if (base + 3 < n) {
        int4 v = *(const int4*)&cnt[base];
        c0 = v.x; c1 = v.y; c2 = v.z; c3 = v.w;
    } else {
        if (base     < n) c0 = cnt[base];
        if (base + 1 < n) c1 = cnt[base + 1];
        if (base + 2 < n) c2 = cnt[base + 2];
        if (base + 3 < n) c3 = cnt[base + 3];
    }
    int tsum = c0 + c1 + c2 + c3;
    sd[t] = tsum; __syncthreads();
    for (int off = 1; off < 256; off <<= 1) {
        int x = (t >= off) ? sd[t - off] : 0;
        __syncthreads();
        sd[t] += x;
        __syncthreads();
    }
    int excl = sd[t] - tsum + boff[b];
    if (base     < n) rowptr[base]     = excl;
    if (base + 1 < n) rowptr[base + 1] = excl + c0;
    if (base + 2 < n) rowptr[base + 2] = excl + c0 + c1;
    if (base + 3 < n) rowptr[base + 3] = excl + c0 + c1 + c2;
}

// atomic-free CSR fill using precomputed ranks
__global__ void fill2_k(const int* __restrict__ src, const int* __restrict__ dst,
                        const int* __restrict__ rank, const int* __restrict__ rowptr,
                        int* __restrict__ colidx, int E) {
    for (int e = blockIdx.x * blockDim.x + threadIdx.x; e < E; e += gridDim.x * blockDim.x) {
        int d = dst[e];
        colidx[rowptr[d] + rank[e]] = src[e];
    }
}

// ---------------- x~ = bf16(x * dinv[row])  [N,64] ----------------

__global__ __launch_bounds__(256) void scale_x_k(const float* __restrict__ x,
                                                 const float* __restrict__ dinv,
                                                 uint* __restrict__ xt, int n) {
    int gid = blockIdx.x * blockDim.x + threadIdx.x;
    if (gid >= n * 8) return;
    int row = gid >> 3, l = gid & 7;
    float dv = dinv[row];
    const float* p = &x[(size_t)row * 64 + l * 8];
    float4 a = *(const float4*)p;
    float4 b = *(const float4*)(p + 4);
    uint4 o;
    o.x = pack_bf2(a.x * dv, a.y * dv);
    o.y = pack_bf2(a.z * dv, a.w * dv);
    o.z = pack_bf2(b.x * dv, b.y * dv);
    o.w = pack_bf2(b.z * dv, b.w * dv);
    *(uint4*)&xt[(size_t)row * 32 + l * 4] = o;
}

// ---------------- gather 64-dim bf16 -> bf16 sum: s~[d] = xt[d] + sum xt[src] ----------------
// 8 lanes/node, 16B per lane

__global__ __launch_bounds__(256) void gather64_k(const uint* __restrict__ xt,
                                                  const int* __restrict__ rowptr,
                                                  const int* __restrict__ colidx,
                                                  uint* __restrict__ st, int n) {
    int lane = threadIdx.x & 7;
    int local = threadIdx.x >> 3;   // 32 nodes/block
    int co = lane * 4;
    for (int node = blockIdx.x * 32 + local; node < n; node += gridDim.x * 32) {
        float a0=0,a1=0,a2=0,a3=0,a4=0,a5=0,a6=0,a7=0;
        uint4 v = *(const uint4*)&xt[(size_t)node * 32 + co];
        acc_bf2(v.x, a0, a1); acc_bf2(v.y, a2, a3);
        acc_bf2(v.z, a4, a5); acc_bf2(v.w, a6, a7);
        int beg = rowptr[node], end = rowptr[node + 1];
        int e = beg;
        for (; e + 3 < end; e += 4) {
            int s0 = colidx[e], s1 = colidx[e+1], s2 = colidx[e+2], s3 = colidx[e+3];
            uint4 v0 = *(const uint4*)&xt[(size_t)s0 * 32 + co];
            uint4 v1 = *(const uint4*)&xt[(size_t)s1 * 32 + co];
            uint4 v2 = *(const uint4*)&xt[(size_t)s2 * 32 + co];
            uint4 v3 = *(const uint4*)&xt[(size_t)s3 * 32 + co];
            acc_bf2(v0.x,a0,a1); acc_bf2(v0.y,a2,a3); acc_bf2(v0.z,a4,a5); acc_bf2(v0.w,a6,a7);
            acc_bf2(v1.x,a0,a1); acc_bf2(v1.y,a2,a3); acc_bf2(v1.z,a4,a5); acc_bf2(v1.w,a6,a7);
            acc_bf2(v2.x,a0,a1); acc_bf2(v2.y,a2,a3); acc_bf2(v2.z,a4,a5); acc_bf2(v2.w,a6,a7);
            acc_bf2(v3.x,a0,a1); acc_bf2(v3.y,a2,a3); acc_bf2(v3.z,a4,a5); acc_bf2(v3.w,a6,a7);
        }
        for (; e < end; e++) {
            uint4 v0 = *(const uint4*)&xt[(size_t)colidx[e] * 32 + co];
            acc_bf2(v0.x,a0,a1); acc_bf2(v0.y,a2,a3); acc_bf2(v0.z,a4,a5); acc_bf2(v0.w,a6,a7);
        }
        uint4 o;
        o.x = pack_bf2(a0, a1);
        o.y = pack_bf2(a2, a3);
        o.z = pack_bf2(a4, a5);
        o.w = pack_bf2(a6, a7);
        *(uint4*)&st[(size_t)node * 32 + co] = o;
    }
}

// ---------------- gather 128-dim bf16 -> out = relu(dinv*(self+sum) + b) f32 ----------------

__global__ __launch_bounds__(256) void gather128_k(const uint* __restrict__ hp,
                                                   const int* __restrict__ rowptr,
                                                   const int* __restrict__ colidx,
                                                   const float* __restrict__ dinv,
                                                   const float* __restrict__ bias,
                                                   float* __restrict__ out, int n) {
    int lane = threadIdx.x & 15;
    int local = threadIdx.x >> 4;   // 16 nodes/block
    int co = lane * 4;
    for (int node = blockIdx.x * 16 + local; node < n; node += gridDim.x * 16) {
        float a0=0,a1=0,a2=0,a3=0,a4=0,a5=0,a6=0,a7=0;
        uint4 v = *(const uint4*)&hp[(size_t)node * 64 + co];
        acc_bf2(v.x, a0, a1); acc_bf2(v.y, a2, a3);
        acc_bf2(v.z, a4, a5); acc_bf2(v.w, a6, a7);
        int beg = rowptr[node], end = rowptr[node + 1];
        int e = beg;
        for (; e + 3 < end; e += 4) {
            int s0 = colidx[e], s1 = colidx[e+1], s2 = colidx[e+2], s3 = colidx[e+3];
            uint4 v0 = *(const uint4*)&hp[(size_t)s0 * 64 + co];
            uint4 v1 = *(const uint4*)&hp[(size_t)s1 * 64 + co];
            uint4 v2 = *(const uint4*)&hp[(size_t)s2 * 64 + co];
            uint4 v3 = *(const uint4*)&hp[(size_t)s3 * 64 + co];
            acc_bf2(v0.x,a0,a1); acc_bf2(v0.y,a2,a3); acc_bf2(v0.z,a4,a5); acc_bf2(v0.w,a6,a7);
            acc_bf2(v1.x,a0,a1); acc_bf2(v1.y,a2,a3); acc_bf2(v1.z,a4,a5); acc_bf2(v1.w,a6,a7);
            acc_bf2(v2.x,a0,a1); acc_bf2(v2.y,a2,a3); acc_bf2(v2.z,a4,a5); acc_bf2(v2.w,a6,a7);
            acc_bf2(v3.x,a0,a1); acc_bf2(v3.y,a2,a3); acc_bf2(v3.z,a4,a5); acc_bf2(v3.w,a6,a7);
        }
        for (; e < end; e++) {
            uint4 v0 = *(const uint4*)&hp[(size_t)colidx[e] * 64 + co];
            acc_bf2(v0.x,a0,a1); acc_bf2(v0.y,a2,a3); acc_bf2(v0.z,a4,a5); acc_bf2(v0.w,a6,a7);
        }
        float dv = dinv[node];
        int jb = lane * 8;
        float4 b0 = *(const float4*)&bias[jb];
        float4 b1 = *(const float4*)&bias[jb + 4];
        float4 o0, o1;
        o0.x = fmaxf(fmaf(dv, a0, b0.x), 0.f);
        o0.y = fmaxf(fmaf(dv, a1, b0.y), 0.f);
        o0.z = fmaxf(fmaf(dv, a2, b0.z), 0.f);
        o0.w = fmaxf(fmaf(dv, a3, b0.w), 0.f);
        o1.x = fmaxf(fmaf(dv, a4, b1.x), 0.f);
        o1.y = fmaxf(fmaf(dv, a5, b1.y), 0.f);
        o1.z = fmaxf(fmaf(dv, a6, b1.z), 0.f);
        o1.w = fmaxf(fmaf(dv, a7, b1.w), 0.f);
        float* o = &out[(size_t)node * 128 + jb];
        *(float4*)o       = o0;
        *(float4*)(o + 4) = o1;
    }
}

// ---------------- W fragment pack: Wf[((nt*KS+ks)*64 + l)*8 + j] = bf16(W[ks*32+(l>>4)*8+j][nt*16+(l&15)]) ----------------

template <int K>
__global__ void pack_w_k(const float* __restrict__ W, ushort* __restrict__ Wf) {
    constexpr int KS = K / 32;
    int gid = blockIdx.x * 256 + threadIdx.x;
    if (gid >= 8 * KS * 512) return;
    int j = gid & 7, l = (gid >> 3) & 63, f = gid >> 9;
    int nt = f / KS, ks = f - nt * KS;
    int k = ks * 32 + ((l >> 4) & 3) * 8 + j;
    int n = nt * 16 + (l & 15);
    Wf[gid] = f2bf(W[k * 128 + n]);
}

// ---------------- MFMA GEMM: Y = A[n,K](bf16) x Wf(K x 128, frag-packed) ----------------
// EPI 0: out = bf16(relu(dinv*acc + bias))   EPI 1: out = bf16(dinv*acc)
// No LDS, no barriers. Wave w of block handles rows [ (bid*4+w)*16 .. +16 ), all 128 cols.
// C/D layout (HW-verified): col = lane&15, row = (lane>>4)*4 + reg.

template <int K, int EPI>
__global__ __launch_bounds__(256) void gemm_mfma_k(const ushort* __restrict__ A,
                                                   const ushort* __restrict__ Wf,
                                                   const float* __restrict__ dinv,
                                                   const float* __restrict__ bias,
                                                   ushort* __restrict__ outb, int n) {
    constexpr int KS = K / 32;
    int wave = threadIdx.x >> 6;
    int lane = threadIdx.x & 63;
    int row0 = (blockIdx.x * 4 + wave) * 16;
    if (row0 >= n) return;
    int m = lane & 15, g = lane >> 4;
    int arow = min(row0 + m, n - 1);

    bf16x8 a[KS];
    const ushort* abase = &A[(size_t)arow * K + g * 8];
#pragma unroll
    for (int ks = 0; ks < KS; ks++)
        a[ks] = *reinterpret_cast<const bf16x8*>(abase + ks * 32);

    f32x4 acc[8];
#pragma unroll
    for (int nt = 0; nt < 8; nt++) {
        acc[nt] = (f32x4){0.f, 0.f, 0.f, 0.f};
#pragma unroll
        for (int ks = 0; ks < KS; ks++) {
            bf16x8 b = *reinterpret_cast<const bf16x8*>(&Wf[((size_t)(nt * KS + ks) * 64 + lane) * 8]);
            acc[nt] = __builtin_amdgcn_mfma_f32_16x16x32_bf16(a[ks], b, acc[nt], 0, 0, 0);
        }
    }

    int orow0 = row0 + g * 4;
#pragma unroll
    for (int r = 0; r < 4; r++) {
        int row = orow0 + r;
        if (row < n) {
            float dvr = dinv[row];
#pragma unroll
            for (int nt = 0; nt < 8; nt++) {
                float v = acc[nt][r] * dvr;
                if (EPI == 0) v = fmaxf(v + bias[nt * 16 + m], 0.f);
                outb[(size_t)row * 128 + nt * 16 + m] = f2bf(v);
            }
        }
    }
}

// ---------------- pool ----------------

__global__ __launch_bounds__(128) void pool_k(const float* __restrict__ h,
                                              const int* __restrict__ batch, int n,
                                              float* __restrict__ sums, float* __restrict__ cnts) {
    int j = threadIdx.x;
    int chunk = (n + gridDim.x - 1) / gridDim.x;
    int i0 = blockIdx.x * chunk;
    int i1 = min(n, i0 + chunk);
    if (i0 >= n) return;
    int cur = batch[i0];
    float acc = 0.f;
    int cnt = 0;
    for (int i = i0; i < i1; i++) {
        int g = batch[i];
        if (g != cur) {
            atomicAdd(&sums[cur * 128 + j], acc);
            if (j == 0) atomicAdd(&cnts[cur], (float)cnt);
            acc = 0.f; cnt = 0; cur = g;
        }
        acc += h[(size_t)i * 128 + j];
        cnt++;
    }
    atomicAdd(&sums[cur * 128 + j], acc);
    if (j == 0) atomicAdd(&cnts[cur], (float)cnt);
}

// ---------------- MLP head ----------------

__global__ __launch_bounds__(64) void mlp_k(const float* __restrict__ sums, const float* __restrict__ cnts,
                                            const float* __restrict__ Wl1, const float* __restrict__ bl1,
                                            const float* __restrict__ Wl2, const float* __restrict__ bl2,
                                            float* __restrict__ out) {
    __shared__ float pooled[128];
    __shared__ float hidden[64];
    int g = blockIdx.x, t = threadIdx.x;
    float c = fmaxf(cnts[g], 1.0f);
    pooled[t]      = sums[g * 128 + t] / c;
    pooled[t + 64] = sums[g * 128 + 64 + t] / c;
    __syncthreads();
    float a = bl1[t];
#pragma unroll 4
    for (int cc = 0; cc < 128; cc++) a = fmaf(pooled[cc], Wl1[cc * 64 + t], a);
    hidden[t] = fmaxf(a, 0.f);
    __syncthreads();
    if (t < 10) {
        float o = bl2[t];
#pragma unroll 8
        for (int jj = 0; jj < 64; jj++) o = fmaf(hidden[jj], Wl2[jj * 10 + t], o);
        out[g * 10 + t] = o;
    }
}

// ---------------- launch ----------------

extern "C" void kernel_launch(void* const* d_in, const int* in_sizes, int n_in,
                              void* d_out, int out_size, void* d_ws, size_t ws_size,
                              hipStream_t stream) {
    const float* x    = (const float*)d_in[0];
    const int*   src  = (const int*)d_in[1];
    const int*   dst  = (const int*)d_in[2];
    const int*   batch= (const int*)d_in[3];
    const float* W1   = (const float*)d_in[4];
    const float* b1   = (const float*)d_in[5];
    const float* W2   = (const float*)d_in[6];
    const float* b2   = (const float*)d_in[7];
    const float* Wl1  = (const float*)d_in[8];
    const float* bl1  = (const float*)d_in[9];
    const float* Wl2  = (const float*)d_in[10];
    const float* bl2  = (const float*)d_in[11];
    float* out = (float*)d_out;

    const int N = NODES_N, E = EDGES_E;

    size_t off = 0;
    auto take = [&](size_t bytes) { size_t o = off; off = (off + bytes + 255) & ~(size_t)255; return o; };
    char* ws = (char*)d_ws;
    ushort* h1b  = (ushort*)(ws + take((size_t)N * 128 * 2));  // h1 bf16
    uint*   h2p  = (uint*)(ws + take((size_t)N * 128 * 2));    // h2' bf16 [N,128] as uint[N,64]
    uint*   stil = (uint*)(ws + take((size_t)N * 64 * 2));     // s~ bf16 [N,64] as uint[N,32]
    uint*   xt   = (uint*)(ws + take((size_t)N * 64 * 2));     // x~ bf16 [N,64]
    float*  bufB = (float*)(ws + take((size_t)N * 128 * 4));   // h2 f32
    float*  dinv = (float*)(ws + take((size_t)N * 4));
    ushort* W1f  = (ushort*)(ws + take((size_t)64 * 128 * 2));
    ushort* W2f  = (ushort*)(ws + take((size_t)128 * 128 * 2));
    size_t zbytes = ((size_t)N + GRAPHS_G * 128 + GRAPHS_G) * 4;
    char*  zbase  = ws + take(zbytes);
    int*   cnt    = (int*)zbase;
    float* sums   = (float*)(zbase + (size_t)N * 4);
    float* cnts   = (float*)(zbase + (size_t)N * 4 + GRAPHS_G * 128 * 4);
    int*   rowptr = (int*)(ws + take((size_t)(N + 1) * 4));
    int*   bsum   = (int*)(ws + take(256 * 4));
    int*   colidx = (int*)(ws + take((size_t)E * 4));
    int*   rank   = (int*)(ws + take((size_t)E * 4));
    (void)ws_size; (void)in_sizes; (void)n_in; (void)out_size;

    hipMemsetAsync(zbase, 0, zbytes, stream);

    // weight packing (independent)
    pack_w_k<64><<<(64 * 128 + 255) / 256, 256, 0, stream>>>(W1, W1f);
    pack_w_k<128><<<(128 * 128 + 255) / 256, 256, 0, stream>>>(W2, W2f);

    // degree (+rank) and CSR
    count_rank_k<<<2048, 256, 0, stream>>>(dst, E, cnt, rank);
    dinv_k<<<(N + 255) / 256, 256, 0, stream>>>(cnt, N, dinv);
    int nb = (N + 1023) / 1024;
    count_reduce_k<<<nb, 256, 0, stream>>>(cnt, N, bsum);
    scan_bsum_k<<<1, 64, 0, stream>>>(bsum, nb, rowptr, N, E);
    write_rowptr_k<<<nb, 256, 0, stream>>>(cnt, N, bsum, rowptr);
    fill2_k<<<2048, 256, 0, stream>>>(src, dst, rank, rowptr, colidx, E);

    // conv1 (aggregate-first): s~ = xt[self] + sum xt[src]; h1 = bf16(relu(dinv*(s~@W1) + b1))
    scale_x_k<<<(N * 8 + 255) / 256, 256, 0, stream>>>(x, dinv, xt, N);
    gather64_k<<<2048, 256, 0, stream>>>(xt, rowptr, colidx, stil, N);
    int gblk = (N + 63) / 64;
    gemm_mfma_k<64, 0><<<gblk, 256, 0, stream>>>((const ushort*)stil, W1f, dinv, b1, h1b, N);

    // conv2: h2' = bf16(dinv*(h1@W2)); h2 = relu(dinv*(self+sum) + b2)
    gemm_mfma_k<128, 1><<<gblk, 256, 0, stream>>>(h1b, W2f, dinv, nullptr, (ushort*)h2p, N);
    gather128_k<<<2048, 256, 0, stream>>>(h2p, rowptr, colidx, dinv, b2, bufB, N);

    // pool + head
    pool_k<<<1024, 128, 0, stream>>>(bufB, batch, N, sums, cnts);
    mlp_k<<<GRAPHS_G, 64, 0, stream>>>(sums, cnts, Wl1, bl1, Wl2, bl2, out);
}